// Round 1
// baseline (10276.460 us; speedup 1.0000x reference)
//
#include <hip/hip_runtime.h>
#include <hip/hip_bf16.h>
#include <cstddef>

#define DD 2048
#define NR 256
#define NCHUNK 16
#define CSZ 128

__device__ __forceinline__ float sigm(float v){ return 1.f/(1.f+__expf(-v)); }
__device__ __forceinline__ float dsilu(float z){ float s = sigm(z); return s*(1.f + z*(1.f - s)); }
// chunk row r (0..255) of chunk t -> row index into x viewed as (4096 x 2048)
__device__ __forceinline__ int xrow(int r, int t){ return (r>>7)*2048 + t*CSZ + (r&127); }

// ---------------------------------------------------------------------------
// C[r, j] = sum_k A[r,k] * B[j,k] + bias[j]   (A: 256xK rows, B: 2048x2048 row-major)
// MODE 0: A = x(chunk t);  store z0 -> o0, silu(z0) -> o1
// MODE 1: A = Ac (h);      store dpred = 2/N * (pred - x_chunk) -> o0
// MODE 2: A = x(chunk t);  store silu -> o0
// MODE 3: A = Ac (h2);     store pred -> o0 at chunk-mapped rows (d_out)
// ---------------------------------------------------------------------------
template<int MODE>
__global__ __launch_bounds__(256) void gemm_rxT(
    const float* __restrict__ x, int t,
    const float* __restrict__ Ac,
    const float* __restrict__ B_,
    const float* __restrict__ bias,
    float* __restrict__ o0,
    float* __restrict__ o1)
{
  __shared__ float As[16][68];
  __shared__ float Bs[16][68];
  const int tid = threadIdx.x;
  const int tx = tid & 15, ty = tid >> 4;
  const int j0 = blockIdx.x * 64;
  const int r0 = blockIdx.y * 64;
  float acc[4][4] = {};
  for (int k0 = 0; k0 < DD; k0 += 16) {
#pragma unroll
    for (int it = 0; it < 4; ++it) {
      int rr = (tid >> 4) + it*16;
      int kk = tid & 15;
      float av;
      if (MODE == 0 || MODE == 2) av = x[(size_t)xrow(r0+rr, t)*DD + k0 + kk];
      else                        av = Ac[(size_t)(r0+rr)*DD + k0 + kk];
      As[kk][rr] = av;
      Bs[kk][rr] = B_[(size_t)(j0+rr)*DD + k0 + kk];
    }
    __syncthreads();
#pragma unroll
    for (int kk = 0; kk < 16; ++kk) {
      float a[4], b[4];
#pragma unroll
      for (int i=0;i<4;++i) a[i] = As[kk][ty*4+i];
#pragma unroll
      for (int j=0;j<4;++j) b[j] = Bs[kk][tx*4+j];
#pragma unroll
      for (int i=0;i<4;++i)
#pragma unroll
        for (int j=0;j<4;++j)
          acc[i][j] += a[i]*b[j];
    }
    __syncthreads();
  }
  const float4 b4 = *reinterpret_cast<const float4*>(&bias[j0 + tx*4]);
  const float bb[4] = {b4.x, b4.y, b4.z, b4.w};
#pragma unroll
  for (int i=0;i<4;++i){
    int r = r0 + ty*4 + i;
    float4 v0, v1;
    float* p0 = (float*)&v0; float* p1 = (float*)&v1;
    if (MODE == 1){
      float4 xv4 = *reinterpret_cast<const float4*>(&x[(size_t)xrow(r,t)*DD + j0 + tx*4]);
      const float xv[4] = {xv4.x, xv4.y, xv4.z, xv4.w};
#pragma unroll
      for (int j=0;j<4;++j) p0[j] = (2.f/524288.f)*((acc[i][j] + bb[j]) - xv[j]);
    } else {
#pragma unroll
      for (int j=0;j<4;++j){
        float v = acc[i][j] + bb[j];
        if (MODE == 0){ p0[j] = v; p1[j] = v * sigm(v); }
        else if (MODE == 2){ p0[j] = v * sigm(v); }
        else { p0[j] = v; }
      }
    }
    if (MODE == 3)
      *reinterpret_cast<float4*>(&o0[(size_t)xrow(r,t)*DD + j0 + tx*4]) = v0;
    else
      *reinterpret_cast<float4*>(&o0[(size_t)r*DD + j0 + tx*4]) = v0;
    if (MODE == 0)
      *reinterpret_cast<float4*>(&o1[(size_t)r*DD + j0 + tx*4]) = v1;
  }
}

// ---------------------------------------------------------------------------
// dz0[r,m] = (sum_d dpred[r,d] * W1[d,m]) * dsilu(z0[r,m])
// ---------------------------------------------------------------------------
__global__ __launch_bounds__(256) void gemm_nn_dz0(
    const float* __restrict__ dpred,
    const float* __restrict__ W1c,
    const float* __restrict__ z0,
    float* __restrict__ dz0)
{
  __shared__ float As[16][68];
  __shared__ float Bs[16][68];
  const int tid = threadIdx.x;
  const int tx = tid & 15, ty = tid >> 4;
  const int j0 = blockIdx.x * 64;
  const int r0 = blockIdx.y * 64;
  float acc[4][4] = {};
  for (int k0 = 0; k0 < DD; k0 += 16) {
#pragma unroll
    for (int it = 0; it < 4; ++it) {
      int rr = (tid >> 4) + it*16;
      int kk = tid & 15;
      As[kk][rr] = dpred[(size_t)(r0+rr)*DD + k0 + kk];
    }
#pragma unroll
    for (int it = 0; it < 4; ++it) {
      int kk = (tid >> 6) + it*4;
      int jj = tid & 63;
      Bs[kk][jj] = W1c[(size_t)(k0+kk)*DD + j0 + jj];
    }
    __syncthreads();
#pragma unroll
    for (int kk = 0; kk < 16; ++kk) {
      float a[4], b[4];
#pragma unroll
      for (int i=0;i<4;++i) a[i] = As[kk][ty*4+i];
#pragma unroll
      for (int j=0;j<4;++j) b[j] = Bs[kk][tx*4+j];
#pragma unroll
      for (int i=0;i<4;++i)
#pragma unroll
        for (int j=0;j<4;++j)
          acc[i][j] += a[i]*b[j];
    }
    __syncthreads();
  }
#pragma unroll
  for (int i=0;i<4;++i){
    int r = r0 + ty*4 + i;
    float4 z4 = *reinterpret_cast<const float4*>(&z0[(size_t)r*DD + j0 + tx*4]);
    const float zz[4] = {z4.x, z4.y, z4.z, z4.w};
    float4 v0; float* p0 = (float*)&v0;
#pragma unroll
    for (int j=0;j<4;++j) p0[j] = acc[i][j] * dsilu(zz[j]);
    *reinterpret_cast<float4*>(&dz0[(size_t)r*DD + j0 + tx*4]) = v0;
  }
}

// ---------------------------------------------------------------------------
// G[i,j] = sum_{r=0..255} P[r,i] * Q[r,j]   (QX: Q = x chunk t)
// ---------------------------------------------------------------------------
template<bool QX>
__global__ __launch_bounds__(256) void gemm_grad(
    const float* __restrict__ P,
    const float* __restrict__ Q,
    const float* __restrict__ x, int t,
    float* __restrict__ G)
{
  __shared__ float Ps[16][68];
  __shared__ float Qs[16][68];
  const int tid = threadIdx.x;
  const int tx = tid & 15, ty = tid >> 4;
  const int i0 = blockIdx.y * 64;
  const int j0 = blockIdx.x * 64;
  float acc[4][4] = {};
  for (int k0 = 0; k0 < NR; k0 += 16) {
#pragma unroll
    for (int it = 0; it < 4; ++it) {
      int kk = (tid >> 6) + it*4;
      int ii = tid & 63;
      Ps[kk][ii] = P[(size_t)(k0+kk)*DD + i0 + ii];
      float qv;
      if (QX) qv = x[(size_t)xrow(k0+kk, t)*DD + j0 + ii];
      else    qv = Q[(size_t)(k0+kk)*DD + j0 + ii];
      Qs[kk][ii] = qv;
    }
    __syncthreads();
#pragma unroll
    for (int kk = 0; kk < 16; ++kk) {
      float a[4], b[4];
#pragma unroll
      for (int i=0;i<4;++i) a[i] = Ps[kk][ty*4+i];
#pragma unroll
      for (int j=0;j<4;++j) b[j] = Qs[kk][tx*4+j];
#pragma unroll
      for (int i=0;i<4;++i)
#pragma unroll
        for (int j=0;j<4;++j)
          acc[i][j] += a[i]*b[j];
    }
    __syncthreads();
  }
#pragma unroll
  for (int i=0;i<4;++i){
    float4 v0; float* p0 = (float*)&v0;
#pragma unroll
    for (int j=0;j<4;++j) p0[j] = acc[i][j];
    *reinterpret_cast<float4*>(&G[(size_t)(i0+ty*4+i)*DD + j0 + tx*4]) = v0;
  }
}

// gb[j] = sum_{r=0..255} src[r, j]
__global__ void colsum256(const float* __restrict__ src, float* __restrict__ dst){
  int j = blockIdx.x * blockDim.x + threadIdx.x;
  float s = 0.f;
  for (int r = 0; r < NR; ++r) s += src[(size_t)r*DD + j];
  dst[j] = s;
}

// per-row dots with lr_w / fg_w; accumulate sigmoid(lr) and raw fg sums
__global__ __launch_bounds__(256) void rowdots(
    const float* __restrict__ x, int t,
    const float* __restrict__ lr_w, const float* __restrict__ lr_b,
    const float* __restrict__ fg_w,
    float* __restrict__ accs)
{
  int r = blockIdx.x;
  const float* xr = x + (size_t)xrow(r,t)*DD;
  float sl = 0.f, sf = 0.f;
  for (int i = threadIdx.x; i < DD; i += 256){
    float xv = xr[i];
    sl += xv * lr_w[i];
    sf += xv * fg_w[i];
  }
#pragma unroll
  for (int off = 32; off > 0; off >>= 1){
    sl += __shfl_down(sl, off);
    sf += __shfl_down(sf, off);
  }
  __shared__ float smA[4], smB[4];
  int w = threadIdx.x >> 6;
  if ((threadIdx.x & 63) == 0){ smA[w] = sl; smB[w] = sf; }
  __syncthreads();
  if (threadIdx.x == 0){
    float dl = smA[0]+smA[1]+smA[2]+smA[3];
    float df = smB[0]+smB[1]+smB[2]+smB[3];
    atomicAdd(&accs[0], sigm(dl + lr_b[0]));
    atomicAdd(&accs[1 + (r>>7)], df);
  }
}

__global__ void finalize(float* __restrict__ accs, const float* __restrict__ fg_b,
                         float* __restrict__ scal){
  float eff_lr = 0.01f * accs[0] * (1.f/256.f);
  float fgt = 0.5f*( sigm(accs[1]*(1.f/128.f) + fg_b[0]) + sigm(accs[2]*(1.f/128.f) + fg_b[0]) );
  scal[0] = eff_lr; scal[1] = fgt;
  accs[0] = 0.f; accs[1] = 0.f; accs[2] = 0.f;
}

__global__ __launch_bounds__(256) void update(
    float* __restrict__ W0c, float* __restrict__ W1c,
    float* __restrict__ b0c, float* __restrict__ b1c,
    const float* __restrict__ gW0, const float* __restrict__ gW1,
    const float* __restrict__ gb0, const float* __restrict__ gb1,
    const float* __restrict__ scal)
{
  const float lr = scal[0], fg = scal[1];
  const int total = 2*2048*2048 + 2*2048;
  for (int idx = blockIdx.x*256 + threadIdx.x; idx < total; idx += gridDim.x*256){
    if (idx < 4194304)            W0c[idx] = fg*W0c[idx] - lr*gW0[idx];
    else if (idx < 8388608){ int i = idx - 4194304; W1c[i] = fg*W1c[i] - lr*gW1[i]; }
    else if (idx < 8390656){ int i = idx - 8388608; b0c[i] = fg*b0c[i] - lr*gb0[i]; }
    else                  { int i = idx - 8390656; b1c[i] = fg*b1c[i] - lr*gb1[i]; }
  }
}

extern "C" void kernel_launch(void* const* d_in, const int* in_sizes, int n_in,
                              void* d_out, int out_size, void* d_ws, size_t ws_size,
                              hipStream_t stream)
{
  const float* x    = (const float*)d_in[0];
  const float* W0   = (const float*)d_in[1];
  const float* b0   = (const float*)d_in[2];
  const float* W1   = (const float*)d_in[3];
  const float* b1   = (const float*)d_in[4];
  const float* lr_w = (const float*)d_in[5];
  const float* lr_b = (const float*)d_in[6];
  const float* fg_w = (const float*)d_in[7];
  const float* fg_b = (const float*)d_in[8];
  float* out = (float*)d_out;

  float* ws = (float*)d_ws;
  size_t off = 0;
  float* W0c = ws + off; off += 4194304;
  float* W1c = ws + off; off += 4194304;
  float* b0c = ws + off; off += 2048;
  float* b1c = ws + off; off += 2048;
  float* z0  = ws + off; off += 524288;
  float* h   = ws + off; off += 524288;
  float* dp  = ws + off; off += 524288;
  float* dz  = ws + off; off += 524288;
  float* gW0 = ws + off; off += 4194304;
  float* gW1 = ws + off; off += 4194304;
  float* gb0 = ws + off; off += 2048;
  float* gb1 = ws + off; off += 2048;
  float* accs= ws + off; off += 8;
  float* scal= ws + off; off += 8;

  hipMemcpyAsync(W0c, W0, 4194304*sizeof(float), hipMemcpyDeviceToDevice, stream);
  hipMemcpyAsync(W1c, W1, 4194304*sizeof(float), hipMemcpyDeviceToDevice, stream);
  hipMemcpyAsync(b0c, b0, 2048*sizeof(float), hipMemcpyDeviceToDevice, stream);
  hipMemcpyAsync(b1c, b1, 2048*sizeof(float), hipMemcpyDeviceToDevice, stream);
  hipMemsetAsync(accs, 0, 8*sizeof(float), stream);

  dim3 blk(256);
  dim3 gRow(32, 4), gGrad(32, 32);
  for (int t = 0; t < NCHUNK; ++t){
    // forward 1 (old params): z0, h
    gemm_rxT<0><<<gRow, blk, 0, stream>>>(x, t, nullptr, W0c, b0c, z0, h);
    // pred -> dpred
    gemm_rxT<1><<<gRow, blk, 0, stream>>>(x, t, h, W1c, b1c, dp, nullptr);
    // grads
    gemm_grad<false><<<gGrad, blk, 0, stream>>>(dp, h, x, t, gW1);
    colsum256<<<8, 256, 0, stream>>>(dp, gb1);
    gemm_nn_dz0<<<gRow, blk, 0, stream>>>(dp, W1c, z0, dz);
    gemm_grad<true><<<gGrad, blk, 0, stream>>>(dz, nullptr, x, t, gW0);
    colsum256<<<8, 256, 0, stream>>>(dz, gb0);
    // gates
    rowdots<<<256, blk, 0, stream>>>(x, t, lr_w, lr_b, fg_w, accs);
    finalize<<<1, 1, 0, stream>>>(accs, fg_b, scal);
    // param update
    update<<<4096, blk, 0, stream>>>(W0c, W1c, b0c, b1c, gW0, gW1, gb0, gb1, scal);
    // forward 2 (new params) -> out
    gemm_rxT<2><<<gRow, blk, 0, stream>>>(x, t, nullptr, W0c, b0c, h, nullptr);
    gemm_rxT<3><<<gRow, blk, 0, stream>>>(x, t, h, W1c, b1c, out, nullptr);
  }
}

// Round 2
// 2449.593 us; speedup vs baseline: 4.1952x; 4.1952x over previous
//
#include <hip/hip_runtime.h>
#include <hip/hip_bf16.h>
#include <cstddef>

#define DD 2048
#define NRW 256
#define NCHUNK 16
#define CSZ 128
#define SCDP 4096.0f

typedef _Float16 h16;
typedef __attribute__((ext_vector_type(8))) _Float16 f16x8;
typedef __attribute__((ext_vector_type(4))) _Float16 f16x4;
typedef __attribute__((ext_vector_type(4))) float f32x4;

__device__ __forceinline__ float sigm(float v){ return 1.f/(1.f+__expf(-v)); }
// chunk row r (0..255) of chunk t -> row index into x viewed as (4096 x 2048)
__device__ __forceinline__ int xrow(int r, int t){ return (r>>7)*2048 + t*CSZ + (r&127); }

__device__ __forceinline__ f32x4 mfma16(f16x8 a, f16x8 b, f32x4 c){
  return __builtin_amdgcn_mfma_f32_16x16x32_f16(a, b, c, 0, 0, 0);
}

// ---------------------------------------------------------------------------
// Row GEMM: C[r,j] = sum_k A[r,k]*Bm[j,k] (+bias[j]);  A: 256x2048 h16,
// Bm: 2048x2048 h16 (N,K row-major). Tile 32(M) x 64(N), BK=64, 4 waves.
// MODE 0 (fwd1):  v=acc+b0; store dsilu(v)->of32, silu(v)->ob + obT
// MODE 1 (pred):  v=acc+b1; dp=(SCDP*2/N)*(v - x[chunk]); -> ob + obT
// MODE 2 (dz):    v=acc;    dz=v*ds0; -> obT only
// MODE 3 (fwd2a): v=acc+b0; silu(v) -> ob
// MODE 4 (fwd2b): v=acc+b1; -> of32 at chunk-mapped rows (d_out)
// ---------------------------------------------------------------------------
template<int MODE>
__global__ __launch_bounds__(256) void rowgemm(
    const h16* __restrict__ A, const h16* __restrict__ Bm,
    const float* __restrict__ bias,
    const float* __restrict__ x, int t,
    const float* __restrict__ ds0,
    float* __restrict__ of32,
    h16* __restrict__ ob, h16* __restrict__ obT)
{
  __shared__ __align__(16) h16 As[32][72];
  __shared__ __align__(16) h16 Bs[64][72];
  __shared__ __align__(16) h16 Tb[64][48];
  const int tid = threadIdx.x;
  const int j0 = blockIdx.x * 64;
  const int r0 = blockIdx.y * 32;
  const int trow = tid >> 3, t8 = tid & 7;
  const int wid = tid >> 6, lane = tid & 63;
  const int wm = wid >> 1, wn = wid & 1;
  const int lr_ = lane & 15, lk = lane >> 4;
  f32x4 acc0 = {0.f,0.f,0.f,0.f}, acc1 = {0.f,0.f,0.f,0.f};
  for (int k0 = 0; k0 < DD; k0 += 64){
    f16x8 av  = *(const f16x8*)&A [(size_t)(r0+trow)*DD + k0 + t8*8];
    f16x8 bv0 = *(const f16x8*)&Bm[(size_t)(j0+trow)*DD + k0 + t8*8];
    f16x8 bv1 = *(const f16x8*)&Bm[(size_t)(j0+trow+32)*DD + k0 + t8*8];
    *(f16x8*)&As[trow][t8*8] = av;
    *(f16x8*)&Bs[trow][t8*8] = bv0;
    *(f16x8*)&Bs[trow+32][t8*8] = bv1;
    __syncthreads();
    f16x8 a0  = *(const f16x8*)&As[wm*16+lr_][lk*8];
    f16x8 a1  = *(const f16x8*)&As[wm*16+lr_][32+lk*8];
    f16x8 b00 = *(const f16x8*)&Bs[wn*32+lr_][lk*8];
    f16x8 b01 = *(const f16x8*)&Bs[wn*32+lr_][32+lk*8];
    f16x8 b10 = *(const f16x8*)&Bs[wn*32+16+lr_][lk*8];
    f16x8 b11 = *(const f16x8*)&Bs[wn*32+16+lr_][32+lk*8];
    acc0 = mfma16(a0,b00,acc0); acc0 = mfma16(a1,b01,acc0);
    acc1 = mfma16(a0,b10,acc1); acc1 = mfma16(a1,b11,acc1);
    __syncthreads();
  }
  const int grbase = r0 + wm*16 + lk*4;
#pragma unroll
  for (int jj = 0; jj < 2; ++jj){
    const f32x4 acc = jj ? acc1 : acc0;
    const int gc = j0 + wn*32 + jj*16 + lr_;
    float bv = (MODE != 2) ? bias[gc] : 0.f;
#pragma unroll
    for (int ii = 0; ii < 4; ++ii){
      const int gr = grbase + ii;
      float v = acc[ii] + bv;
      if (MODE == 0){
        float s = sigm(v);
        float hval = v*s;
        of32[(size_t)gr*DD + gc] = s*(1.f + v*(1.f - s));   // dsilu
        ob[(size_t)gr*DD + gc] = (h16)hval;
        Tb[wn*32 + jj*16 + lr_][wm*16 + lk*4 + ii] = (h16)hval;
      } else if (MODE == 1){
        float xv = x[(size_t)xrow(gr,t)*DD + gc];
        float dpv = (SCDP*2.f/524288.f)*(v - xv);
        ob[(size_t)gr*DD + gc] = (h16)dpv;
        Tb[wn*32 + jj*16 + lr_][wm*16 + lk*4 + ii] = (h16)dpv;
      } else if (MODE == 2){
        float dzv = v * ds0[(size_t)gr*DD + gc];
        Tb[wn*32 + jj*16 + lr_][wm*16 + lk*4 + ii] = (h16)dzv;
      } else if (MODE == 3){
        float s = sigm(v);
        ob[(size_t)gr*DD + gc] = (h16)(v*s);
      } else {
        of32[(size_t)xrow(gr,t)*DD + gc] = v;
      }
    }
  }
  if (MODE == 0 || MODE == 1 || MODE == 2){
    __syncthreads();
    const int lrow = tid >> 2;
    const int c8 = (tid & 3)*8;
    *(f16x8*)&obT[(size_t)(j0+lrow)*NRW + r0 + c8] = *(const f16x8*)&Tb[lrow][c8];
  }
}

// ---------------------------------------------------------------------------
// Grad GEMM + fused update. G[i,j] = sum_r A[i,r]*Bm[j,r]; A,Bm: 2048x256 h16.
// W = fg*W - (lr/SCDP)*G, writes fp32 master + h16 copy (+ h16 transposed, MODE0).
// Tile 64x64, BK=64, 4 waves each 32x32.
// ---------------------------------------------------------------------------
template<int MODE> // 0: W1 (writes WTh), 1: W0
__global__ __launch_bounds__(256) void gradup(
    const h16* __restrict__ A, const h16* __restrict__ Bm,
    float* __restrict__ Wc, h16* __restrict__ Wh, h16* __restrict__ WTh,
    const float* __restrict__ scal)
{
  __shared__ __align__(16) h16 As[64][72];
  __shared__ __align__(16) h16 Bs[64][72];
  __shared__ __align__(16) h16 Tb[64][72];
  const int tid = threadIdx.x;
  const int j0 = blockIdx.x * 64;
  const int i0 = blockIdx.y * 64;
  const int trow = tid >> 3, t8 = tid & 7;
  const int wid = tid >> 6, lane = tid & 63;
  const int wm = wid >> 1, wn = wid & 1;
  const int lr_ = lane & 15, lk = lane >> 4;
  f32x4 acc[2][2] = {};
  for (int k0 = 0; k0 < NRW; k0 += 64){
    *(f16x8*)&As[trow][t8*8]    = *(const f16x8*)&A [(size_t)(i0+trow)*NRW + k0 + t8*8];
    *(f16x8*)&As[trow+32][t8*8] = *(const f16x8*)&A [(size_t)(i0+trow+32)*NRW + k0 + t8*8];
    *(f16x8*)&Bs[trow][t8*8]    = *(const f16x8*)&Bm[(size_t)(j0+trow)*NRW + k0 + t8*8];
    *(f16x8*)&Bs[trow+32][t8*8] = *(const f16x8*)&Bm[(size_t)(j0+trow+32)*NRW + k0 + t8*8];
    __syncthreads();
#pragma unroll
    for (int s = 0; s < 2; ++s){
      f16x8 a0 = *(const f16x8*)&As[wm*32+lr_][s*32+lk*8];
      f16x8 a1 = *(const f16x8*)&As[wm*32+16+lr_][s*32+lk*8];
      f16x8 b0 = *(const f16x8*)&Bs[wn*32+lr_][s*32+lk*8];
      f16x8 b1 = *(const f16x8*)&Bs[wn*32+16+lr_][s*32+lk*8];
      acc[0][0] = mfma16(a0,b0,acc[0][0]);
      acc[0][1] = mfma16(a0,b1,acc[0][1]);
      acc[1][0] = mfma16(a1,b0,acc[1][0]);
      acc[1][1] = mfma16(a1,b1,acc[1][1]);
    }
    __syncthreads();
  }
  const float lrs = scal[0] * (1.f/SCDP);
  const float fg  = scal[1];
#pragma unroll
  for (int ri=0;ri<2;++ri)
#pragma unroll
  for (int cj=0;cj<2;++cj)
#pragma unroll
  for (int ii=0;ii<4;++ii){
    const int gi = i0 + wm*32 + ri*16 + lk*4 + ii;
    const int gj = j0 + wn*32 + cj*16 + lr_;
    const size_t idx = (size_t)gi*DD + gj;
    float wv = fg*Wc[idx] - lrs*acc[ri][cj][ii];
    Wc[idx] = wv;
    Wh[idx] = (h16)wv;
    if (MODE==0) Tb[wn*32+cj*16+lr_][wm*32+ri*16+lk*4+ii] = (h16)wv;
  }
  if (MODE==0){
    __syncthreads();
    const int lrow = tid >> 2;
    const int c16 = (tid & 3)*16;
    *(f16x8*)&WTh[(size_t)(j0+lrow)*DD + i0 + c16]   = *(const f16x8*)&Tb[lrow][c16];
    *(f16x8*)&WTh[(size_t)(j0+lrow)*DD + i0 + c16+8] = *(const f16x8*)&Tb[lrow][c16+8];
  }
}

// x chunk -> h16 row-major + h16 transposed
__global__ __launch_bounds__(256) void xprep(const float* __restrict__ x, int t,
    h16* __restrict__ xh, h16* __restrict__ xT)
{
  __shared__ __align__(16) h16 Tb[64][72];
  const int tid = threadIdx.x;
  const int j0 = blockIdx.x*64, r0 = blockIdx.y*64;
  const int c4 = (tid & 15)*4, rbase = tid >> 4;
#pragma unroll
  for (int i=0;i<4;++i){
    int row = rbase + i*16;
    float4 xv = *(const float4*)&x[(size_t)xrow(r0+row, t)*DD + j0 + c4];
    f16x4 hv; hv[0]=(h16)xv.x; hv[1]=(h16)xv.y; hv[2]=(h16)xv.z; hv[3]=(h16)xv.w;
    *(f16x4*)&xh[(size_t)(r0+row)*DD + j0 + c4] = hv;
    Tb[c4+0][row]=hv[0]; Tb[c4+1][row]=hv[1]; Tb[c4+2][row]=hv[2]; Tb[c4+3][row]=hv[3];
  }
  __syncthreads();
  const int lcol = tid >> 2, r16 = (tid & 3)*16;
  *(f16x8*)&xT[(size_t)(j0+lcol)*NRW + r0 + r16]   = *(const f16x8*)&Tb[lcol][r16];
  *(f16x8*)&xT[(size_t)(j0+lcol)*NRW + r0 + r16+8] = *(const f16x8*)&Tb[lcol][r16+8];
}

__global__ __launch_bounds__(256) void init_w1(const float* __restrict__ Wc,
    h16* __restrict__ Wh, h16* __restrict__ WTh)
{
  __shared__ __align__(16) h16 Tb[64][72];
  const int tid = threadIdx.x;
  const int j0 = blockIdx.x*64, i0 = blockIdx.y*64;
  const int c4 = (tid & 15)*4, rbase = tid >> 4;
#pragma unroll
  for (int i=0;i<4;++i){
    int row = rbase + i*16;
    float4 wv = *(const float4*)&Wc[(size_t)(i0+row)*DD + j0 + c4];
    f16x4 hv; hv[0]=(h16)wv.x; hv[1]=(h16)wv.y; hv[2]=(h16)wv.z; hv[3]=(h16)wv.w;
    *(f16x4*)&Wh[(size_t)(i0+row)*DD + j0 + c4] = hv;
    Tb[c4+0][row]=hv[0]; Tb[c4+1][row]=hv[1]; Tb[c4+2][row]=hv[2]; Tb[c4+3][row]=hv[3];
  }
  __syncthreads();
  const int lrow = tid >> 2, c16 = (tid & 3)*16;
  *(f16x8*)&WTh[(size_t)(j0+lrow)*DD + i0 + c16]   = *(const f16x8*)&Tb[lrow][c16];
  *(f16x8*)&WTh[(size_t)(j0+lrow)*DD + i0 + c16+8] = *(const f16x8*)&Tb[lrow][c16+8];
}

__global__ void init_w0(const float* __restrict__ Wc, h16* __restrict__ Wh){
  size_t i = ((size_t)blockIdx.x*256 + threadIdx.x)*4;
  float4 wv = *(const float4*)&Wc[i];
  f16x4 hv; hv[0]=(h16)wv.x; hv[1]=(h16)wv.y; hv[2]=(h16)wv.z; hv[3]=(h16)wv.w;
  *(f16x4*)&Wh[i] = hv;
}

// gb = rowsum of transposed (scaled) grads; b = fg*b - (lr/SCDP)*gb
__global__ __launch_bounds__(256) void bias_update(
    const h16* __restrict__ dpT, const h16* __restrict__ dzT,
    float* __restrict__ b1c, float* __restrict__ b0c,
    const float* __restrict__ scal)
{
  const int j = blockIdx.x*256 + threadIdx.x;   // 0..4095
  const float lrs = scal[0] * (1.f/SCDP), fg = scal[1];
  const h16* src = (j < DD) ? &dpT[(size_t)j*NRW] : &dzT[(size_t)(j-DD)*NRW];
  float s = 0.f;
  const f16x8* p = (const f16x8*)src;
#pragma unroll 4
  for (int q = 0; q < 32; ++q){
    f16x8 v = p[q];
#pragma unroll
    for (int e = 0; e < 8; ++e) s += (float)v[e];
  }
  if (j < DD) b1c[j]    = fg*b1c[j]    - lrs*s;
  else        b0c[j-DD] = fg*b0c[j-DD] - lrs*s;
}

// gates (exact fp32, unchanged from passing round-1 version)
__global__ __launch_bounds__(256) void rowdots(
    const float* __restrict__ x, int t,
    const float* __restrict__ lr_w, const float* __restrict__ lr_b,
    const float* __restrict__ fg_w,
    float* __restrict__ accs)
{
  int r = blockIdx.x;
  const float* xr = x + (size_t)xrow(r,t)*DD;
  float sl = 0.f, sf = 0.f;
  for (int i = threadIdx.x; i < DD; i += 256){
    float xv = xr[i];
    sl += xv * lr_w[i];
    sf += xv * fg_w[i];
  }
#pragma unroll
  for (int off = 32; off > 0; off >>= 1){
    sl += __shfl_down(sl, off);
    sf += __shfl_down(sf, off);
  }
  __shared__ float smA[4], smB[4];
  int w = threadIdx.x >> 6;
  if ((threadIdx.x & 63) == 0){ smA[w] = sl; smB[w] = sf; }
  __syncthreads();
  if (threadIdx.x == 0){
    float dl = smA[0]+smA[1]+smA[2]+smA[3];
    float df = smB[0]+smB[1]+smB[2]+smB[3];
    atomicAdd(&accs[0], sigm(dl + lr_b[0]));
    atomicAdd(&accs[1 + (r>>7)], df);
  }
}

__global__ void finalize(float* __restrict__ accs, const float* __restrict__ fg_b,
                         float* __restrict__ scal){
  float eff_lr = 0.01f * accs[0] * (1.f/256.f);
  float fgt = 0.5f*( sigm(accs[1]*(1.f/128.f) + fg_b[0]) + sigm(accs[2]*(1.f/128.f) + fg_b[0]) );
  scal[0] = eff_lr; scal[1] = fgt;
  accs[0] = 0.f; accs[1] = 0.f; accs[2] = 0.f;
}

extern "C" void kernel_launch(void* const* d_in, const int* in_sizes, int n_in,
                              void* d_out, int out_size, void* d_ws, size_t ws_size,
                              hipStream_t stream)
{
  const float* x    = (const float*)d_in[0];
  const float* W0   = (const float*)d_in[1];
  const float* b0   = (const float*)d_in[2];
  const float* W1   = (const float*)d_in[3];
  const float* b1   = (const float*)d_in[4];
  const float* lr_w = (const float*)d_in[5];
  const float* lr_b = (const float*)d_in[6];
  const float* fg_w = (const float*)d_in[7];
  const float* fg_b = (const float*)d_in[8];
  float* out = (float*)d_out;

  char* ws = (char*)d_ws;
  size_t off = 0;
  auto alloc = [&](size_t bytes)->char*{ char* p = ws + off; off += (bytes + 255) & ~255ull; return p; };
  float* W0c = (float*)alloc(4194304*4);
  float* W1c = (float*)alloc(4194304*4);
  float* b0c = (float*)alloc(2048*4);
  float* b1c = (float*)alloc(2048*4);
  float* ds0 = (float*)alloc(524288*4);
  float* accs= (float*)alloc(64);
  float* scal= (float*)alloc(64);
  h16* W0h  = (h16*)alloc(4194304*2);
  h16* W1h  = (h16*)alloc(4194304*2);
  h16* W1Th = (h16*)alloc(4194304*2);
  h16* xh   = (h16*)alloc(524288*2);
  h16* xT   = (h16*)alloc(524288*2);
  h16* hb   = (h16*)alloc(524288*2);
  h16* hT   = (h16*)alloc(524288*2);
  h16* dpb  = (h16*)alloc(524288*2);
  h16* dpT  = (h16*)alloc(524288*2);
  h16* dzT  = (h16*)alloc(524288*2);
  h16* h2b  = (h16*)alloc(524288*2);

  hipMemcpyAsync(W0c, W0, 4194304*sizeof(float), hipMemcpyDeviceToDevice, stream);
  hipMemcpyAsync(W1c, W1, 4194304*sizeof(float), hipMemcpyDeviceToDevice, stream);
  hipMemcpyAsync(b0c, b0, 2048*sizeof(float), hipMemcpyDeviceToDevice, stream);
  hipMemcpyAsync(b1c, b1, 2048*sizeof(float), hipMemcpyDeviceToDevice, stream);
  hipMemsetAsync(accs, 0, 64, stream);

  dim3 blk(256);
  init_w0<<<4096, blk, 0, stream>>>(W0c, W0h);
  init_w1<<<dim3(32,32), blk, 0, stream>>>(W1c, W1h, W1Th);

  for (int t = 0; t < NCHUNK; ++t){
    xprep<<<dim3(32,4), blk, 0, stream>>>(x, t, xh, xT);
    rowdots<<<256, blk, 0, stream>>>(x, t, lr_w, lr_b, fg_w, accs);
    finalize<<<1, 1, 0, stream>>>(accs, fg_b, scal);
    // fwd1: z0 = x@W0^T+b0 -> ds0(dsilu), h (row+T)
    rowgemm<0><<<dim3(32,8), blk, 0, stream>>>(xh, W0h, b0c, nullptr, t, nullptr, ds0, hb, hT);
    // pred -> dp (scaled) row+T
    rowgemm<1><<<dim3(32,8), blk, 0, stream>>>(hb, W1h, b1c, x, t, nullptr, nullptr, dpb, dpT);
    // dz = (dp@W1)*dsilu -> dzT
    rowgemm<2><<<dim3(32,8), blk, 0, stream>>>(dpb, W1Th, nullptr, nullptr, t, ds0, nullptr, nullptr, dzT);
    // W1 <- fg*W1 - lr*(dp^T h) ; also refresh W1h, W1Th
    gradup<0><<<dim3(32,32), blk, 0, stream>>>(dpT, hT, W1c, W1h, W1Th, scal);
    // W0 <- fg*W0 - lr*(dz^T x)
    gradup<1><<<dim3(32,32), blk, 0, stream>>>(dzT, xT, W0c, W0h, nullptr, scal);
    bias_update<<<16, blk, 0, stream>>>(dpT, dzT, b1c, b0c, scal);
    // re-forward with updated weights
    rowgemm<3><<<dim3(32,8), blk, 0, stream>>>(xh, W0h, b0c, nullptr, t, nullptr, nullptr, h2b, nullptr);
    rowgemm<4><<<dim3(32,8), blk, 0, stream>>>(h2b, W1h, b1c, nullptr, t, nullptr, out, nullptr, nullptr);
  }
}

// Round 3
// 1731.497 us; speedup vs baseline: 5.9350x; 1.4147x over previous
//
#include <hip/hip_runtime.h>
#include <hip/hip_bf16.h>
#include <cstddef>
#include <cstdint>

#define DD 2048
#define NRW 256
#define NCHUNK 16
#define CSZ 128
#define SCDP 4096.0f
#define NSTEP 16

typedef _Float16 h16;
typedef __attribute__((ext_vector_type(8))) _Float16 f16x8;
typedef __attribute__((ext_vector_type(4))) _Float16 f16x4;
typedef __attribute__((ext_vector_type(4))) float f32x4;

__device__ __forceinline__ float sigm(float v){ return 1.f/(1.f+__expf(-v)); }
// chunk row r (0..255) of chunk t -> row index into x viewed as (4096 x 2048)
__device__ __forceinline__ int xrow(int r, int t){ return (r>>7)*2048 + t*CSZ + (r&127); }
__device__ __forceinline__ f32x4 mfma16(f16x8 a, f16x8 b, f32x4 c){
  return __builtin_amdgcn_mfma_f32_16x16x32_f16(a, b, c, 0, 0, 0);
}

#define SBAR() do{ __builtin_amdgcn_sched_barrier(0); __builtin_amdgcn_s_barrier(); __builtin_amdgcn_sched_barrier(0); }while(0)
#define VMCNT(n) asm volatile("s_waitcnt vmcnt(" #n ")" ::: "memory")

__device__ __forceinline__ void gload16(const h16* g, h16* l){
  __builtin_amdgcn_global_load_lds((const __attribute__((address_space(1))) void*)g,
                                   (__attribute__((address_space(3))) void*)l, 16, 0, 0);
}

// ---------------------------------------------------------------------------
// Row GEMM: C[r,j] = sum_k A[r,k]*Bm[j,k] (+bias[j]);  A: 256x2048 h16,
// Bm: 2048x2048 h16 (N,K row-major). Tile 32(M)x64(N), BK=128, 8 waves,
// 3-buffer global_load_lds pipeline, counted vmcnt, XOR-swizzled LDS.
// ---------------------------------------------------------------------------
template<int MODE>
__global__ __launch_bounds__(512) void rowgemm(
    const h16* __restrict__ A, const h16* __restrict__ Bm,
    const float* __restrict__ bias,
    const float* __restrict__ x, int t,
    const h16* __restrict__ dsin, h16* __restrict__ dsout,
    float* __restrict__ ofp,
    h16* __restrict__ ob, h16* __restrict__ obT)
{
  __shared__ __align__(16) h16 As[3][32][128];
  __shared__ __align__(16) h16 Bs[3][64][128];
  __shared__ __align__(16) h16 Tb[64][36];
  const int tid = threadIdx.x;
  const int j0 = blockIdx.x * 64;
  const int r0 = blockIdx.y * 32;
  const int wid = tid >> 6, lane = tid & 63;
  const int wm = wid >> 2, wn = wid & 3;
  const int lr_ = lane & 15, lk = lane >> 4;
  const int sl4 = lane >> 4, su = lane & 15;
  const int arow = wid*4 + sl4;
  const int brow0 = wid*4 + sl4;
  const int brow1 = 32 + wid*4 + sl4;
  const size_t aoff  = (size_t)(r0 + arow)*DD + (size_t)((su ^ (arow&7))*8);
  const size_t boff0 = (size_t)(j0 + brow0)*DD + (size_t)((su ^ (brow0&7))*8);
  const size_t boff1 = (size_t)(j0 + brow1)*DD + (size_t)((su ^ (brow1&7))*8);
  h16* const as_base = &As[0][0][0];
  h16* const bs_base = &Bs[0][0][0];

  auto STAGE = [&](int b, int s){
    const size_t k0 = (size_t)s*128;
    gload16(A  + aoff  + k0, as_base + b*4096 + wid*512);
    gload16(Bm + boff0 + k0, bs_base + b*8192 + wid*512);
    gload16(Bm + boff1 + k0, bs_base + b*8192 + (wid+8)*512);
  };

  const int ar = wm*16 + lr_;
  const int br = wn*16 + lr_;
  int aidx[4], bidx[4];
#pragma unroll
  for (int q=0;q<4;++q){
    aidx[q] = ar*128 + ((q*4+lk)^(ar&7))*8;
    bidx[q] = br*128 + ((q*4+lk)^(br&7))*8;
  }

  f32x4 acc = {0.f,0.f,0.f,0.f};
  STAGE(0,0); STAGE(1,1);
  for (int s = 0; s < NSTEP; ++s){
    if (s < NSTEP-2){ STAGE((s+2)%3, s+2); VMCNT(6); }
    else if (s == NSTEP-2){ VMCNT(3); }
    else { VMCNT(0); }
    SBAR();
    const int cur = s%3;
    f16x8 a[4], b[4];
#pragma unroll
    for (int q=0;q<4;++q){
      a[q] = *(const f16x8*)(as_base + cur*4096 + aidx[q]);
      b[q] = *(const f16x8*)(bs_base + cur*8192 + bidx[q]);
    }
#pragma unroll
    for (int q=0;q<4;++q) acc = mfma16(a[q], b[q], acc);
    SBAR();
  }

  const int gc = j0 + wn*16 + lr_;
  const float bv = (MODE != 2) ? bias[gc] : 0.f;
#pragma unroll
  for (int ii=0;ii<4;++ii){
    const int gr = r0 + wm*16 + lk*4 + ii;
    float v = acc[ii] + bv;
    if (MODE == 0){
      float sg = sigm(v);
      float hval = v*sg;
      dsout[(size_t)gr*DD + gc] = (h16)(sg*(1.f + v*(1.f - sg)));
      ob[(size_t)gr*DD + gc] = (h16)hval;
      Tb[wn*16 + lr_][wm*16 + lk*4 + ii] = (h16)hval;
    } else if (MODE == 1){
      float xv = x[(size_t)xrow(gr,t)*DD + gc];
      float dpv = (SCDP*2.f/524288.f)*(v - xv);
      ob[(size_t)gr*DD + gc] = (h16)dpv;
      Tb[wn*16 + lr_][wm*16 + lk*4 + ii] = (h16)dpv;
    } else if (MODE == 2){
      float dzv = v * (float)dsin[(size_t)gr*DD + gc];
      Tb[wn*16 + lr_][wm*16 + lk*4 + ii] = (h16)dzv;
    } else if (MODE == 3){
      float sg = sigm(v);
      ob[(size_t)gr*DD + gc] = (h16)(v*sg);
    } else {
      ofp[(size_t)xrow(gr,t)*DD + gc] = v;
    }
  }
  if (MODE == 0 || MODE == 1 || MODE == 2){
    __syncthreads();
    const int lrow = tid >> 3, c4 = (tid & 7)*4;
    *(f16x4*)&obT[(size_t)(j0+lrow)*NRW + r0 + c4] = *(const f16x4*)&Tb[lrow][c4];
  }
}

// ---------------------------------------------------------------------------
// Grad GEMM + fused h16 weight update. G[i,j] = sum_r A[i,r]*Bm[j,r].
// ---------------------------------------------------------------------------
template<int MODE> // 0: W1 (also writes WTh), 1: W0
__global__ __launch_bounds__(256) void gradup(
    const h16* __restrict__ A, const h16* __restrict__ Bm,
    h16* __restrict__ Wh, h16* __restrict__ WTh,
    const float* __restrict__ scal)
{
  __shared__ __align__(16) h16 As[2][64][128];
  __shared__ __align__(16) h16 Bs[2][64][128];
  __shared__ __align__(16) h16 Tb[64][72];
  const int tid = threadIdx.x;
  const int j0 = blockIdx.x * 64;
  const int i0 = blockIdx.y * 64;
  const int wid = tid >> 6, lane = tid & 63;
  const int wm = wid >> 1, wn = wid & 1;
  const int lr_ = lane & 15, lk = lane >> 4;
  const int sl4 = lane >> 4, su = lane & 15;
  h16* const as_base = &As[0][0][0];
  h16* const bs_base = &Bs[0][0][0];

#pragma unroll
  for (int h=0; h<2; ++h){
#pragma unroll
    for (int i=0;i<4;++i){
      const int c = wid*4 + i;
      const int row = c*4 + sl4;
      const size_t go = (size_t)row*NRW + (size_t)(h*128 + ((su ^ (row&7))*8));
      gload16(A  + (size_t)i0*NRW + go, as_base + h*8192 + c*512);
      gload16(Bm + (size_t)j0*NRW + go, bs_base + h*8192 + c*512);
    }
  }

  const int ra0 = wm*32 + lr_, ra1 = ra0 + 16;
  const int rb0 = wn*32 + lr_, rb1 = rb0 + 16;
  f32x4 acc[2][2] = {};
#pragma unroll
  for (int h=0; h<2; ++h){
    if (h==0){ VMCNT(8); } else { VMCNT(0); }
    SBAR();
#pragma unroll
    for (int ks=0; ks<4; ++ks){
      f16x8 a0 = *(const f16x8*)(as_base + h*8192 + ra0*128 + ((ks*4+lk)^(ra0&7))*8);
      f16x8 a1 = *(const f16x8*)(as_base + h*8192 + ra1*128 + ((ks*4+lk)^(ra1&7))*8);
      f16x8 b0 = *(const f16x8*)(bs_base + h*8192 + rb0*128 + ((ks*4+lk)^(rb0&7))*8);
      f16x8 b1 = *(const f16x8*)(bs_base + h*8192 + rb1*128 + ((ks*4+lk)^(rb1&7))*8);
      acc[0][0] = mfma16(a0,b0,acc[0][0]);
      acc[0][1] = mfma16(a0,b1,acc[0][1]);
      acc[1][0] = mfma16(a1,b0,acc[1][0]);
      acc[1][1] = mfma16(a1,b1,acc[1][1]);
    }
  }

  const float lrs = scal[0] * (1.f/SCDP);
  const float fg  = scal[1];
#pragma unroll
  for (int ri=0;ri<2;++ri)
#pragma unroll
  for (int cj=0;cj<2;++cj)
#pragma unroll
  for (int ii=0;ii<4;++ii){
    const int gi = i0 + wm*32 + ri*16 + lk*4 + ii;
    const int gj = j0 + wn*32 + cj*16 + lr_;
    const size_t idx = (size_t)gi*DD + gj;
    float wv = fg*(float)Wh[idx] - lrs*acc[ri][cj][ii];
    Wh[idx] = (h16)wv;
    if (MODE==0) Tb[wn*32+cj*16+lr_][wm*32+ri*16+lk*4+ii] = (h16)wv;
  }
  if (MODE==0){
    __syncthreads();
    const int lrow = tid >> 2, c16 = (tid & 3)*16;
    *(f16x8*)&WTh[(size_t)(j0+lrow)*DD + i0 + c16]   = *(const f16x8*)&Tb[lrow][c16];
    *(f16x8*)&WTh[(size_t)(j0+lrow)*DD + i0 + c16+8] = *(const f16x8*)&Tb[lrow][c16+8];
  }
}

// x chunk -> h16 row-major + transposed; fused lr/fg gate partial dots
__global__ __launch_bounds__(256) void xprep(const float* __restrict__ x, int t,
    const float* __restrict__ lr_w, const float* __restrict__ fg_w,
    h16* __restrict__ xh, h16* __restrict__ xT,
    float* __restrict__ rowacc, float* __restrict__ accs)
{
  __shared__ __align__(16) h16 Tb[64][72];
  __shared__ float red[4];
  const int tid = threadIdx.x;
  const int j0 = blockIdx.x*64, r0 = blockIdx.y*64;
  const int c4 = (tid & 15)*4, g = tid >> 4;
  const float4 lw = *(const float4*)&lr_w[j0+c4];
  const float4 fw = *(const float4*)&fg_w[j0+c4];
  float sfall = 0.f;
  float slv[4];
#pragma unroll
  for (int i=0;i<4;++i){
    const int row = g + i*16;
    float4 xv = *(const float4*)&x[(size_t)xrow(r0+row, t)*DD + j0 + c4];
    f16x4 hv; hv[0]=(h16)xv.x; hv[1]=(h16)xv.y; hv[2]=(h16)xv.z; hv[3]=(h16)xv.w;
    *(f16x4*)&xh[(size_t)(r0+row)*DD + j0 + c4] = hv;
    Tb[c4+0][row]=hv[0]; Tb[c4+1][row]=hv[1]; Tb[c4+2][row]=hv[2]; Tb[c4+3][row]=hv[3];
    float sl = xv.x*lw.x + xv.y*lw.y + xv.z*lw.z + xv.w*lw.w;
    float sf = xv.x*fw.x + xv.y*fw.y + xv.z*fw.z + xv.w*fw.w;
#pragma unroll
    for (int m=1;m<16;m<<=1) sl += __shfl_xor(sl, m);
    slv[i] = sl;
    sfall += sf;
  }
#pragma unroll
  for (int m=1;m<64;m<<=1) sfall += __shfl_xor(sfall, m);
  if ((tid&63)==0) red[tid>>6] = sfall;
  __syncthreads();
  if ((tid&15)==0){
#pragma unroll
    for (int i=0;i<4;++i) atomicAdd(&rowacc[r0 + g + i*16], slv[i]);
  }
  if (tid==0) atomicAdd(&accs[1 + (blockIdx.y>>1)], red[0]+red[1]+red[2]+red[3]);
  const int lcol = tid >> 2, r16 = (tid & 3)*16;
  *(f16x8*)&xT[(size_t)(j0+lcol)*NRW + r0 + r16]   = *(const f16x8*)&Tb[lcol][r16];
  *(f16x8*)&xT[(size_t)(j0+lcol)*NRW + r0 + r16+8] = *(const f16x8*)&Tb[lcol][r16+8];
}

__global__ __launch_bounds__(256) void finalize(
    float* __restrict__ rowacc, float* __restrict__ accs,
    const float* __restrict__ lr_b, const float* __restrict__ fg_b,
    float* __restrict__ scal)
{
  __shared__ float red[256];
  const int tid = threadIdx.x;
  float s = sigm(rowacc[tid] + lr_b[0]);
  rowacc[tid] = 0.f;
  red[tid] = s; __syncthreads();
  for (int o=128;o>0;o>>=1){ if (tid<o) red[tid]+=red[tid+o]; __syncthreads(); }
  if (tid==0){
    scal[0] = 0.01f * red[0] * (1.f/256.f);
    scal[1] = 0.5f*( sigm(accs[1]*(1.f/128.f) + fg_b[0]) + sigm(accs[2]*(1.f/128.f) + fg_b[0]) );
    accs[1] = 0.f; accs[2] = 0.f;
  }
}

__global__ __launch_bounds__(256) void bias_update(
    const h16* __restrict__ dpT, const h16* __restrict__ dzT,
    float* __restrict__ b1c, float* __restrict__ b0c,
    const float* __restrict__ scal)
{
  const int j = blockIdx.x*256 + threadIdx.x;
  const float lrs = scal[0] * (1.f/SCDP), fg = scal[1];
  const h16* src = (j < DD) ? &dpT[(size_t)j*NRW] : &dzT[(size_t)(j-DD)*NRW];
  float s = 0.f;
  const f16x8* p = (const f16x8*)src;
#pragma unroll 4
  for (int q = 0; q < 32; ++q){
    f16x8 v = p[q];
#pragma unroll
    for (int e = 0; e < 8; ++e) s += (float)v[e];
  }
  if (j < DD) b1c[j]    = fg*b1c[j]    - lrs*s;
  else        b0c[j-DD] = fg*b0c[j-DD] - lrs*s;
}

__global__ __launch_bounds__(256) void init_w1(const float* __restrict__ Wc,
    h16* __restrict__ Wh, h16* __restrict__ WTh)
{
  __shared__ __align__(16) h16 Tb[64][72];
  const int tid = threadIdx.x;
  const int j0 = blockIdx.x*64, i0 = blockIdx.y*64;
  const int c4 = (tid & 15)*4, rbase = tid >> 4;
#pragma unroll
  for (int i=0;i<4;++i){
    int row = rbase + i*16;
    float4 wv = *(const float4*)&Wc[(size_t)(i0+row)*DD + j0 + c4];
    f16x4 hv; hv[0]=(h16)wv.x; hv[1]=(h16)wv.y; hv[2]=(h16)wv.z; hv[3]=(h16)wv.w;
    *(f16x4*)&Wh[(size_t)(i0+row)*DD + j0 + c4] = hv;
    Tb[c4+0][row]=hv[0]; Tb[c4+1][row]=hv[1]; Tb[c4+2][row]=hv[2]; Tb[c4+3][row]=hv[3];
  }
  __syncthreads();
  const int lrow = tid >> 2, c16 = (tid & 3)*16;
  *(f16x8*)&WTh[(size_t)(j0+lrow)*DD + i0 + c16]   = *(const f16x8*)&Tb[lrow][c16];
  *(f16x8*)&WTh[(size_t)(j0+lrow)*DD + i0 + c16+8] = *(const f16x8*)&Tb[lrow][c16+8];
}

__global__ void init_w0(const float* __restrict__ Wc, h16* __restrict__ Wh){
  size_t i = ((size_t)blockIdx.x*256 + threadIdx.x)*4;
  float4 wv = *(const float4*)&Wc[i];
  f16x4 hv; hv[0]=(h16)wv.x; hv[1]=(h16)wv.y; hv[2]=(h16)wv.z; hv[3]=(h16)wv.w;
  *(f16x4*)&Wh[i] = hv;
}

extern "C" void kernel_launch(void* const* d_in, const int* in_sizes, int n_in,
                              void* d_out, int out_size, void* d_ws, size_t ws_size,
                              hipStream_t stream)
{
  const float* x    = (const float*)d_in[0];
  const float* W0   = (const float*)d_in[1];
  const float* b0   = (const float*)d_in[2];
  const float* W1   = (const float*)d_in[3];
  const float* b1   = (const float*)d_in[4];
  const float* lr_w = (const float*)d_in[5];
  const float* lr_b = (const float*)d_in[6];
  const float* fg_w = (const float*)d_in[7];
  const float* fg_b = (const float*)d_in[8];
  float* out = (float*)d_out;

  char* ws = (char*)d_ws;
  size_t off = 0;
  auto alloc = [&](size_t bytes)->char*{ char* p = ws + off; off += (bytes + 255) & ~255ull; return p; };
  float* b0c    = (float*)alloc(2048*4);
  float* b1c    = (float*)alloc(2048*4);
  float* stats  = (float*)alloc(1312);
  float* rowacc = stats;
  float* accs   = stats + 256;
  float* scal   = stats + 264;
  h16* W0h  = (h16*)alloc(4194304*2);
  h16* W1h  = (h16*)alloc(4194304*2);
  h16* W1Th = (h16*)alloc(4194304*2);
  h16* ds0h = (h16*)alloc(524288*2);
  h16* xh   = (h16*)alloc(524288*2);
  h16* xT   = (h16*)alloc(524288*2);
  h16* hb   = (h16*)alloc(524288*2);
  h16* hT   = (h16*)alloc(524288*2);
  h16* dpb  = (h16*)alloc(524288*2);
  h16* dpT  = (h16*)alloc(524288*2);
  h16* dzT  = (h16*)alloc(524288*2);
  h16* h2b  = (h16*)alloc(524288*2);

  hipMemcpyAsync(b0c, b0, 2048*sizeof(float), hipMemcpyDeviceToDevice, stream);
  hipMemcpyAsync(b1c, b1, 2048*sizeof(float), hipMemcpyDeviceToDevice, stream);
  hipMemsetAsync(stats, 0, 264*4, stream);

  dim3 blk256(256), blk512(512);
  init_w0<<<4096, blk256, 0, stream>>>(W0, W0h);
  init_w1<<<dim3(32,32), blk256, 0, stream>>>(W1, W1h, W1Th);

  for (int t = 0; t < NCHUNK; ++t){
    xprep<<<dim3(32,4), blk256, 0, stream>>>(x, t, lr_w, fg_w, xh, xT, rowacc, accs);
    finalize<<<1, blk256, 0, stream>>>(rowacc, accs, lr_b, fg_b, scal);
    rowgemm<0><<<dim3(32,8), blk512, 0, stream>>>(xh, W0h, b0c, nullptr, t, nullptr, ds0h, nullptr, hb, hT);
    rowgemm<1><<<dim3(32,8), blk512, 0, stream>>>(hb, W1h, b1c, x, t, nullptr, nullptr, nullptr, dpb, dpT);
    rowgemm<2><<<dim3(32,8), blk512, 0, stream>>>(dpb, W1Th, b1c, nullptr, t, ds0h, nullptr, nullptr, nullptr, dzT);
    gradup<0><<<dim3(32,32), blk256, 0, stream>>>(dpT, hT, W1h, W1Th, scal);
    gradup<1><<<dim3(32,32), blk256, 0, stream>>>(dzT, xT, W0h, nullptr, scal);
    bias_update<<<16, blk256, 0, stream>>>(dpT, dzT, b1c, b0c, scal);
    rowgemm<3><<<dim3(32,8), blk512, 0, stream>>>(xh, W0h, b0c, nullptr, t, nullptr, nullptr, nullptr, h2b, nullptr);
    rowgemm<4><<<dim3(32,8), blk512, 0, stream>>>(h2b, W1h, b1c, nullptr, t, nullptr, nullptr, out, nullptr, nullptr);
  }
}